// Round 4
// baseline (700.578 us; speedup 1.0000x reference)
//
#include <hip/hip_runtime.h>
#include <math.h>

#define NB   256
#define ND   63
#define NN   3969        // 63*63
#define MIDc 32

__device__ __forceinline__ float gelu_f(float v){
    return 0.5f * v * (1.0f + erff(v * 0.70710678118654752440f));
}

#define FMA4(A, W, S) { (A).x=fmaf((W).x,(S),(A).x); (A).y=fmaf((W).y,(S),(A).y); \
                        (A).z=fmaf((W).z,(S),(A).z); (A).w=fmaf((W).w,(S),(A).w); }

union F4 { float4 v; float a[4]; };
union W16 { float4 v[4]; float a[16]; };

// ---------------- DFT tables (64x64 padded, row/col 63 zeroed) + acc reset ----
__global__ void k_tables(float* __restrict__ Fr, float* __restrict__ Fi, float* __restrict__ acc){
    int idx = blockIdx.x * blockDim.x + threadIdx.x;
    if (idx < 4096){
        int r = idx >> 6, c = idx & 63;
        float vr = 0.f, vi = 0.f;
        if (r < 63 && c < 63){
            int m = (r * c) % 63;
            float ang = 6.283185307179586f * (float)m / 63.0f;
            vr = cosf(ang); vi = -sinf(ang);
        }
        Fr[idx] = vr; Fi[idx] = vi;
    }
    if (idx == 0) acc[0] = 0.f;
}

// -------- weight prep: ct1 [1,32,3,3]->[tap][32]; ct2-4 ->[tap][ci][co32]; ct5 ->[tap][ci][2]
__global__ void k_wprep(const float* __restrict__ w1, const float* __restrict__ w2,
                        const float* __restrict__ w3, const float* __restrict__ w4,
                        const float* __restrict__ w5,
                        float* __restrict__ o1, float* __restrict__ o2,
                        float* __restrict__ o3, float* __restrict__ o4,
                        float* __restrict__ o5){
    int idx = blockIdx.x * blockDim.x + threadIdx.x;
    if (idx < 9216){
        int co = idx & 31, t = idx >> 5;
        int ci = t & 31, tap = t >> 5;
        int ky = tap / 3, kx = tap % 3;
        int src = ((ci*32 + co)*3 + ky)*3 + kx;
        o2[idx] = w2[src]; o3[idx] = w3[src]; o4[idx] = w4[src];
    }
    if (idx < 576){
        int co = idx & 1, t = idx >> 1;
        int ci = t & 31, tap = t >> 5;
        int ky = tap / 3, kx = tap % 3;
        o5[idx] = w5[((ci*2 + co)*3 + ky)*3 + kx];
    }
    if (idx < 288){
        int co = idx & 31, tap = idx >> 5;
        int ky = tap / 3, kx = tap % 3;
        o1[idx] = w1[(co*3 + ky)*3 + kx];
    }
}

// ---------------- hypernet: per-sample 9->100(gelu)->147, twice --------------
__global__ void k_hyper(const float* __restrict__ kA,
                        const float* __restrict__ w1a, const float* __restrict__ b1a,
                        const float* __restrict__ w2a, const float* __restrict__ b2a,
                        const float* __restrict__ w1b, const float* __restrict__ b1b,
                        const float* __restrict__ w2b, const float* __restrict__ b2b,
                        float* __restrict__ out1, float* __restrict__ out2){
    __shared__ float a[9];
    __shared__ float hid[100];
    int b = blockIdx.x, tid = threadIdx.x;
    if (tid < 9) a[tid] = kA[b*9 + tid];
    __syncthreads();
    if (tid < 100){
        float s = b1a[tid];
        #pragma unroll
        for (int i = 0; i < 9; i++) s = fmaf(a[i], w1a[i*100 + tid], s);
        hid[tid] = gelu_f(s);
    }
    __syncthreads();
    if (tid < 147){
        float s = b2a[tid];
        for (int k = 0; k < 100; k++) s = fmaf(hid[k], w2a[k*147 + tid], s);
        out1[b*147 + tid] = s;
    }
    __syncthreads();
    if (tid < 100){
        float s = b1b[tid];
        #pragma unroll
        for (int i = 0; i < 9; i++) s = fmaf(a[i], w1b[i*100 + tid], s);
        hid[tid] = gelu_f(s);
    }
    __syncthreads();
    if (tid < 147){
        float s = b2b[tid];
        for (int k = 0; k < 100; k++) s = fmaf(hid[k], w2b[k*147 + tid], s);
        out2[b*147 + tid] = s;
    }
}

// ---------------- ct1: 1->32, 3x3 in -> 5x5 out, stride2 pad1, gelu, channel-last
__global__ void k_ct1c(const float* __restrict__ kA, const float* __restrict__ wT1,
                       const float* __restrict__ bias, float* __restrict__ out){
    int idx = blockIdx.x * blockDim.x + threadIdx.x;
    if (idx >= NB*25) return;
    int p = idx % 25, b = idx / 25;
    int oy = p / 5, ox = p % 5;
    F4 acc[8];
    #pragma unroll
    for (int q = 0; q < 8; q++) acc[q].v = ((const float4*)bias)[q];
    int nky, kyA[2], iyA[2];
    if (oy & 1){ nky=2; kyA[0]=0; iyA[0]=(oy+1)/2; kyA[1]=2; iyA[1]=(oy-1)/2; }
    else       { nky=1; kyA[0]=1; iyA[0]=oy/2; kyA[1]=1; iyA[1]=0; }
    int nkx, kxA[2], ixA[2];
    if (ox & 1){ nkx=2; kxA[0]=0; ixA[0]=(ox+1)/2; kxA[1]=2; ixA[1]=(ox-1)/2; }
    else       { nkx=1; kxA[0]=1; ixA[0]=ox/2; kxA[1]=1; ixA[1]=0; }
    const float* ab = kA + b*9;
    for (int yi = 0; yi < nky; yi++)
    for (int xi = 0; xi < nkx; xi++){
        float v = ab[iyA[yi]*3 + ixA[xi]];
        const float4* wq = (const float4*)(wT1 + (kyA[yi]*3 + kxA[xi])*32);
        #pragma unroll
        for (int q = 0; q < 8; q++){ float4 w = wq[q]; FMA4(acc[q].v, w, v); }
    }
    float* ob = out + (size_t)idx*32;
    #pragma unroll
    for (int q = 0; q < 8; q++){
        float4 g; g.x=gelu_f(acc[q].a[0]); g.y=gelu_f(acc[q].a[1]);
        g.z=gelu_f(acc[q].a[2]); g.w=gelu_f(acc[q].a[3]);
        ((float4*)ob)[q] = g;
    }
}

// ------------- ct 32->32, stride2 pad1 k3, gelu. channel-last in/out. -------
// Block = sample (all 32 co). Unit = 8 consecutive out px x 8 co; cog minor in
// lane order so 4 lanes fill each pixel's full 128B channel line (coalesced).
template<int HIN>
__global__ __launch_bounds__(256) void k_ct32c(const float* __restrict__ in,
                                               const float* __restrict__ wT,
                                               const float* __restrict__ bias,
                                               float* __restrict__ out){
    constexpr int HOUT = 2*HIN - 1;
    constexpr int HINP = (HIN + 3) & ~3;
    constexpr int OCT  = (HOUT + 7) / 8;
    constexpr int UPR  = OCT * 4;              // 4 co-groups of 8
    constexpr int NODD = (HOUT/2) * UPR;
    constexpr int TOT  = HOUT * UPR;
    __shared__ __align__(16) float in_s[32*HIN*HINP + 16];
    __shared__ __align__(16) float w_s[9216];          // [tap][ci][co32]
    __shared__ __align__(16) float bias_s[32];
    const int b = blockIdx.x;
    const int tid = threadIdx.x;
    { const float4* src = (const float4*)wT; float4* dst = (float4*)w_s;
      for (int i = tid; i < 2304; i += 256) dst[i] = src[i]; }
    if (tid < 32) bias_s[tid] = bias[tid];
    { const float* gi = in + (size_t)b * (32*HIN*HIN);
      for (int i = tid; i < 32*HIN*HIN; i += 256){
        int ci = i & 31, px = i >> 5;
        int y = px / HIN, x = px % HIN;
        in_s[ci*(HIN*HINP) + y*HINP + x] = gi[i];
      } }
    __syncthreads();
    float* ob0 = out + (size_t)b*(HOUT*HOUT*32);
    for (int u = tid; u < TOT; u += 256){
        int r, s;
        if (u < NODD){ r = 2*(u/UPR) + 1; s = u % UPR; }
        else { int v = u - NODD; r = 2*(v/UPR); s = v % UPR; }
        const int m = s >> 2, cog = s & 3;
        const int x4 = 4*m;
        F4 acc[8][2];
        { float4 b0 = ((const float4*)bias_s)[cog*2];
          float4 b1 = ((const float4*)bias_s)[cog*2+1];
          #pragma unroll
          for (int p = 0; p < 8; p++){ acc[p][0].v = b0; acc[p][1].v = b1; } }
        int nky, kyA[2], iyA[2];
        if (r & 1){ int rI = r >> 1; nky = 2; kyA[0]=0; iyA[0]=rI+1; kyA[1]=2; iyA[1]=rI; }
        else      { nky = 1; kyA[0]=1; iyA[0]= r >> 1; kyA[1]=1; iyA[1]=0; }
        for (int yi = 0; yi < nky; yi++){
            const float* ip = in_s + iyA[yi]*HINP + x4;
            const float* wp = w_s + kyA[yi]*3*1024 + cog*8;
            #pragma unroll 2
            for (int ci = 0; ci < 32; ci++){
                F4 iv0, iv1;
                iv0.v = *(const float4*)(ip);
                iv1.v = *(const float4*)(ip + 4);
                float4 w0a = *(const float4*)(wp);
                float4 w0b = *(const float4*)(wp + 4);
                float4 w1a = *(const float4*)(wp + 1024);
                float4 w1b = *(const float4*)(wp + 1028);
                float4 w2a = *(const float4*)(wp + 2048);
                float4 w2b = *(const float4*)(wp + 2052);
                #pragma unroll
                for (int p = 0; p < 4; p++){
                    float ev = iv0.a[p];
                    FMA4(acc[2*p][0].v, w1a, ev);
                    FMA4(acc[2*p][1].v, w1b, ev);
                    float o0 = (p < 3) ? iv0.a[p+1] : iv1.a[0];
                    FMA4(acc[2*p+1][0].v, w0a, o0);
                    FMA4(acc[2*p+1][1].v, w0b, o0);
                    FMA4(acc[2*p+1][0].v, w2a, ev);
                    FMA4(acc[2*p+1][1].v, w2b, ev);
                }
                ip += HIN*HINP;
                wp += 32;
            }
        }
        int lim = HOUT - 8*m; if (lim > 8) lim = 8;
        float* ob = ob0 + ((size_t)r*HOUT + 8*m)*32 + cog*8;
        for (int e = 0; e < lim; e++){
            float4 g0, g1;
            g0.x=gelu_f(acc[e][0].a[0]); g0.y=gelu_f(acc[e][0].a[1]);
            g0.z=gelu_f(acc[e][0].a[2]); g0.w=gelu_f(acc[e][0].a[3]);
            g1.x=gelu_f(acc[e][1].a[0]); g1.y=gelu_f(acc[e][1].a[1]);
            g1.z=gelu_f(acc[e][1].a[2]); g1.w=gelu_f(acc[e][1].a[3]);
            *(float4*)(ob + (size_t)e*32)     = g0;
            *(float4*)(ob + (size_t)e*32 + 4) = g1;
        }
    }
}

// ---- ct5 (32->2, stride2 pad2 k3) + buildv fused, block = sample -----------
__global__ __launch_bounds__(256) void k_ct5v(const float* __restrict__ in,
                                              const float* __restrict__ wT5,
                                              const float* __restrict__ bias,
                                              float* __restrict__ vr,
                                              float* __restrict__ vi){
    __shared__ float ws5[576];
    __shared__ float c5s[2*NN];
    const int b = blockIdx.x, tid = threadIdx.x;
    for (int i = tid; i < 576; i += 256) ws5[i] = wT5[i];
    __syncthreads();
    const float* ib = in + (size_t)b * (32*33*33);
    float b0 = bias[0], b1 = bias[1];
    for (int p = tid; p < NN; p += 256){
        int oy = p / ND, ox = p % ND;
        float a0 = b0, a1 = b1;
        int nky, kyA[2], iyA[2];
        if ((oy & 1) == 0){ nky=2; kyA[0]=0; iyA[0]=oy/2+1; kyA[1]=2; iyA[1]=oy/2; }
        else              { nky=1; kyA[0]=1; iyA[0]=(oy+1)/2; kyA[1]=1; iyA[1]=0; }
        int nkx, kxA[2], ixA[2];
        if ((ox & 1) == 0){ nkx=2; kxA[0]=0; ixA[0]=ox/2+1; kxA[1]=2; ixA[1]=ox/2; }
        else              { nkx=1; kxA[0]=1; ixA[0]=(ox+1)/2; kxA[1]=1; ixA[1]=0; }
        for (int yi = 0; yi < nky; yi++)
        for (int xi = 0; xi < nkx; xi++){
            const float* ip = ib + ((size_t)iyA[yi]*33 + ixA[xi])*32;
            const float* wp = ws5 + (kyA[yi]*3 + kxA[xi])*64;
            #pragma unroll 8
            for (int ci = 0; ci < 32; ci++){
                float v = ip[ci];
                a0 = fmaf(v, wp[ci*2],   a0);
                a1 = fmaf(v, wp[ci*2+1], a1);
            }
        }
        c5s[p]      = a0;
        c5s[NN + p] = a1;
    }
    __syncthreads();
    const float sc = 1.0f / 3969.0f;
    for (int i = tid; i < NN; i += 256){
        int ky = i / ND, kx = i % ND;
        float re, im;
        if (kx <= 31){ re = c5s[2*i]; im = c5s[2*i+1]; }
        else {
            int sy = (ND - ky) % ND, sx = ND - kx;
            int o = 2*(sy*ND + sx); re = c5s[o]; im = -c5s[o+1];
        }
        vr[(size_t)b*4032 + ky*64 + kx] = re * sc;
        vi[(size_t)b*4032 + ky*64 + kx] = im * sc;
    }
}

// ---------------- mega solver: 5 x (smoother ; x += hcorrect(residual)) -----
// Block = sample, 256 threads. x lives in LDS (63x64). Smoother planes and
// DFT planes share a 64KB union (sequential use within an iteration).
__global__ __launch_bounds__(256) void k_solve(const float* __restrict__ x0g,
                                               const float* __restrict__ f,
                                               const float* __restrict__ kAg,
                                               const float* __restrict__ w1g,
                                               const float* __restrict__ w2g,
                                               const float* __restrict__ Frg,
                                               const float* __restrict__ Fig,
                                               const float* __restrict__ vrg,
                                               const float* __restrict__ vig,
                                               float* __restrict__ accg){
    __shared__ __align__(16) float U[16384];     // 64 KB union
    __shared__ __align__(16) float xs[4032];     // 63 x 64
    __shared__ float w1s[147], w2s[147], red[4];
    const int b = blockIdx.x, tid = threadIdx.x;
    float* rs = U;                // 63 x 72
    float* tc = U + 4608;         // 63 x 72
    float* sA = U;                // 2 x 4096 (Mr, Mi)
    float* sB = U + 8192;         // 2 x 4096 (Ttr/Ptr, Tti/Pti)
    float4* A40 = (float4*)sA;  float4* A41 = (float4*)(sA + 4096);
    float4* B40 = (float4*)sB;  float4* B41 = (float4*)(sB + 4096);
    const float4* F4r = (const float4*)Frg;
    const float4* F4i = (const float4*)Fig;
    const float* fg = f + (size_t)b*NN;
    float ka[9];
    #pragma unroll
    for (int i = 0; i < 9; i++) ka[i] = kAg[b*9 + i];
    if (tid < 147){ w1s[tid] = w1g[b*147 + tid]; w2s[tid] = w2g[b*147 + tid]; }
    for (int i = tid; i < NN; i += 256) xs[(i/ND)*64 + (i%ND)] = x0g[(size_t)b*NN + i];
    __syncthreads();

    const int kt = tid >> 4, ct = tid & 15;
    const int k0 = kt * 4, c0 = ct * 4;

    for (int it = 0; it < 5; it++){
        // ================= smoother =================
        for (int i = tid; i < 9216; i += 256) U[i] = 0.f;
        __syncthreads();
        for (int i = tid; i < NN; i += 256){
            int y = i / ND, xx = i % ND;
            float s = 0.f;
            #pragma unroll
            for (int dy = 0; dy < 3; dy++){
                int u = y + dy;
                #pragma unroll
                for (int dx = 0; dx < 3; dx++){
                    int v = xx + dx;
                    float p;
                    if (u == 64 || v == 64)    p = 1.0f;
                    else if (u == 0 || v == 0) p = 0.0f;
                    else                       p = xs[(u-1)*64 + (v-1)];
                    s = fmaf(p, ka[dy*3 + dx], s);
                }
            }
            rs[y*72 + 3 + xx] = fg[i] - s;
        }
        __syncthreads();
        float acc2[2][8] = {};
        for (int c = 0; c < 3; c++){
            for (int rep = 0; rep < 2; rep++){
                int u = rep*256 + tid;
                if (u < 504){
                    int y0 = u >> 3, x0c = 8*(u & 7);
                    float a1[8] = {};
                    for (int dy = 0; dy < 7; dy++){
                        int ry = y0 + dy - 3;
                        if (ry < 0 || ry >= 63) continue;
                        W16 w16;
                        const float4* rp = (const float4*)(rs + ry*72 + x0c);
                        w16.v[0]=rp[0]; w16.v[1]=rp[1]; w16.v[2]=rp[2]; w16.v[3]=rp[3];
                        #pragma unroll
                        for (int dx = 0; dx < 7; dx++){
                            float wv = w1s[c*49 + dy*7 + dx];
                            #pragma unroll
                            for (int t = 0; t < 8; t++) a1[t] = fmaf(wv, w16.a[t+dx], a1[t]);
                        }
                    }
                    int nw = 63 - x0c; if (nw > 8) nw = 8;
                    for (int t = 0; t < nw; t++) tc[y0*72 + 3 + x0c + t] = a1[t];
                }
            }
            __syncthreads();
            for (int rep = 0; rep < 2; rep++){
                int u = rep*256 + tid;
                if (u < 504){
                    int y0 = u >> 3, x0c = 8*(u & 7);
                    for (int dy = 0; dy < 7; dy++){
                        int ry = y0 + dy - 3;
                        if (ry < 0 || ry >= 63) continue;
                        W16 w16;
                        const float4* tp = (const float4*)(tc + ry*72 + x0c);
                        w16.v[0]=tp[0]; w16.v[1]=tp[1]; w16.v[2]=tp[2]; w16.v[3]=tp[3];
                        #pragma unroll
                        for (int dx = 0; dx < 7; dx++){
                            float wv = w2s[c*49 + dy*7 + dx];
                            #pragma unroll
                            for (int t = 0; t < 8; t++) acc2[rep][t] = fmaf(wv, w16.a[t+dx], acc2[rep][t]);
                        }
                    }
                }
            }
            __syncthreads();
        }
        for (int rep = 0; rep < 2; rep++){
            int u = rep*256 + tid;
            if (u < 504){
                int y0 = u >> 3, x0c = 8*(u & 7);
                int nw = 63 - x0c; if (nw > 8) nw = 8;
                for (int t = 0; t < nw; t++) xs[y0*64 + x0c + t] += acc2[rep][t];
            }
        }
        __syncthreads();
        // ============ residual of updated x -> sA plane0 ============
        for (int i = tid; i < 4096; i += 256){
            int y = i >> 6, xx = i & 63;
            float val = 0.f;
            if (y < 63 && xx < 63){
                float s = 0.f;
                #pragma unroll
                for (int dy = 0; dy < 3; dy++){
                    int u = y + dy;
                    #pragma unroll
                    for (int dx = 0; dx < 3; dx++){
                        int v = xx + dx;
                        float p;
                        if (u == 64 || v == 64)    p = 1.0f;
                        else if (u == 0 || v == 0) p = 0.0f;
                        else                       p = xs[(u-1)*64 + (v-1)];
                        s = fmaf(p, ka[dy*3 + dx], s);
                    }
                }
                val = fg[y*ND + xx] - s;
            }
            sA[i] = val;
        }
        __syncthreads();
        // ============ spectral correction ============
        {   // Phase A: T = F r  -> Tt in sB
            float tr[4][4] = {}, ti[4][4] = {};
            for (int m = 0; m < 63; m++){
                F4 fr, fi, rv;
                fr.v = F4r[m*16 + kt]; fi.v = F4i[m*16 + kt];
                rv.v = A40[m*16 + ct];
                #pragma unroll
                for (int i = 0; i < 4; i++)
                    #pragma unroll
                    for (int j = 0; j < 4; j++){
                        tr[i][j] = fmaf(fr.a[i], rv.a[j], tr[i][j]);
                        ti[i][j] = fmaf(fi.a[i], rv.a[j], ti[i][j]);
                    }
            }
            #pragma unroll
            for (int j = 0; j < 4; j++){
                F4 sv, si;
                #pragma unroll
                for (int i = 0; i < 4; i++){ sv.a[i] = tr[i][j]; si.a[i] = ti[i][j]; }
                B40[(c0 + j)*16 + kt] = sv.v;
                B41[(c0 + j)*16 + kt] = si.v;
            }
        }
        __syncthreads();
        {   // Phase B: R = T F ; M = R .* v -> sA
            float Rr[4][4] = {}, Ri[4][4] = {};
            for (int n = 0; n < 63; n++){
                F4 ar, ai, fr, fi;
                ar.v = B40[n*16 + kt]; ai.v = B41[n*16 + kt];
                fr.v = F4r[n*16 + ct]; fi.v = F4i[n*16 + ct];
                #pragma unroll
                for (int i = 0; i < 4; i++)
                    #pragma unroll
                    for (int j = 0; j < 4; j++){
                        Rr[i][j] = fmaf(ar.a[i], fr.a[j], Rr[i][j]);
                        Rr[i][j] = fmaf(-ai.a[i], fi.a[j], Rr[i][j]);
                        Ri[i][j] = fmaf(ar.a[i], fi.a[j], Ri[i][j]);
                        Ri[i][j] = fmaf(ai.a[i], fr.a[j], Ri[i][j]);
                    }
            }
            const float4* v4r = (const float4*)(vrg + (size_t)b*4032);
            const float4* v4i = (const float4*)(vig + (size_t)b*4032);
            #pragma unroll
            for (int i = 0; i < 4; i++){
                int k = k0 + i;
                int kk = k < 63 ? k : 62;
                F4 wr, wi, mr, mi;
                wr.v = v4r[kk*16 + ct]; wi.v = v4i[kk*16 + ct];
                #pragma unroll
                for (int j = 0; j < 4; j++){
                    mr.a[j] = Rr[i][j]*wr.a[j] - Ri[i][j]*wi.a[j];
                    mi.a[j] = Rr[i][j]*wi.a[j] + Ri[i][j]*wr.a[j];
                }
                A40[k*16 + ct] = mr.v;
                A41[k*16 + ct] = mi.v;
            }
        }
        __syncthreads();
        {   // Phase D: P = conj(F) M -> Pt in sB
            float Pr[4][4] = {}, Pi[4][4] = {};
            for (int n = 0; n < 63; n++){
                F4 fr, fi, mr, mi;
                fr.v = F4r[n*16 + kt]; fi.v = F4i[n*16 + kt];
                mr.v = A40[n*16 + ct]; mi.v = A41[n*16 + ct];
                #pragma unroll
                for (int i = 0; i < 4; i++)
                    #pragma unroll
                    for (int j = 0; j < 4; j++){
                        Pr[i][j] = fmaf(fr.a[i], mr.a[j], Pr[i][j]);
                        Pr[i][j] = fmaf(fi.a[i], mi.a[j], Pr[i][j]);
                        Pi[i][j] = fmaf(fr.a[i], mi.a[j], Pi[i][j]);
                        Pi[i][j] = fmaf(-fi.a[i], mr.a[j], Pi[i][j]);
                    }
            }
            #pragma unroll
            for (int j = 0; j < 4; j++){
                F4 sv, si;
                #pragma unroll
                for (int i = 0; i < 4; i++){ sv.a[i] = Pr[i][j]; si.a[i] = Pi[i][j]; }
                B40[(c0 + j)*16 + kt] = sv.v;
                B41[(c0 + j)*16 + kt] = si.v;
            }
        }
        __syncthreads();
        {   // Phase E: y = Re(P conj(F)) ; x += y
            float yv[4][4] = {};
            for (int l = 0; l < 63; l++){
                F4 pr, pi, fr, fi;
                pr.v = B40[l*16 + kt]; pi.v = B41[l*16 + kt];
                fr.v = F4r[l*16 + ct]; fi.v = F4i[l*16 + ct];
                #pragma unroll
                for (int i = 0; i < 4; i++)
                    #pragma unroll
                    for (int j = 0; j < 4; j++){
                        yv[i][j] = fmaf(pr.a[i], fr.a[j], yv[i][j]);
                        yv[i][j] = fmaf(pi.a[i], fi.a[j], yv[i][j]);
                    }
            }
            #pragma unroll
            for (int i = 0; i < 4; i++){
                int p = k0 + i;
                if (p < 63){
                    #pragma unroll
                    for (int j = 0; j < 4; j++){
                        int q = c0 + j;
                        if (q < 63) xs[p*64 + q] += yv[i][j];
                    }
                }
            }
        }
        __syncthreads();
    }
    // ================= final residual + norm partial =================
    float s = 0.f;
    for (int i = tid; i < NN; i += 256){
        int y = i / ND, xx = i % ND;
        float cv = 0.f;
        #pragma unroll
        for (int dy = 0; dy < 3; dy++){
            int u = y + dy;
            #pragma unroll
            for (int dx = 0; dx < 3; dx++){
                int v = xx + dx;
                float p;
                if (u == 64 || v == 64)    p = 1.0f;
                else if (u == 0 || v == 0) p = 0.0f;
                else                       p = xs[(u-1)*64 + (v-1)];
                cv = fmaf(p, ka[dy*3 + dx], cv);
            }
        }
        float r = fg[i] - cv;
        s = fmaf(r, r, s);
    }
    #pragma unroll
    for (int off = 32; off > 0; off >>= 1) s += __shfl_down(s, off, 64);
    int lane = tid & 63, w = tid >> 6;
    if (lane == 0) red[w] = s;
    __syncthreads();
    if (tid == 0) atomicAdd(accg, red[0] + red[1] + red[2] + red[3]);
}

__global__ void k_final(const float* __restrict__ acc, float* __restrict__ out){
    if (threadIdx.x == 0 && blockIdx.x == 0) out[0] = sqrtf(acc[0]) * (1.0f/256.0f);
}

// ---------------- host ------------------------------------------------------
extern "C" void kernel_launch(void* const* d_in, const int* in_sizes, int n_in,
                              void* d_out, int out_size, void* d_ws, size_t ws_size,
                              hipStream_t stream){
    const float* x0     = (const float*)d_in[0];
    const float* f      = (const float*)d_in[1];
    const float* kA     = (const float*)d_in[2];
    const float* fc1_w1 = (const float*)d_in[3];
    const float* fc1_b1 = (const float*)d_in[4];
    const float* fc1_w2 = (const float*)d_in[5];
    const float* fc1_b2 = (const float*)d_in[6];
    const float* fc2_w1 = (const float*)d_in[7];
    const float* fc2_b1 = (const float*)d_in[8];
    const float* fc2_w2 = (const float*)d_in[9];
    const float* fc2_b2 = (const float*)d_in[10];
    const float* ct1_w  = (const float*)d_in[11];
    const float* ct1_b  = (const float*)d_in[12];
    const float* ct2_w  = (const float*)d_in[13];
    const float* ct2_b  = (const float*)d_in[14];
    const float* ct3_w  = (const float*)d_in[15];
    const float* ct3_b  = (const float*)d_in[16];
    const float* ct4_w  = (const float*)d_in[17];
    const float* ct4_b  = (const float*)d_in[18];
    const float* ct5_w  = (const float*)d_in[19];
    const float* ct5_b  = (const float*)d_in[20];
    float* out = (float*)d_out;

    float* ws = (float*)d_ws;
    size_t off = 0;
    auto take = [&](size_t n){ float* p = ws + off; off += (n + 63) & ~(size_t)63; return p; };
    float* Fr  = take(4096);
    float* Fi  = take(4096);
    float* acc = take(64);
    float* w1b = take((size_t)NB*147);
    float* w2b = take((size_t)NB*147);
    float* vr  = take((size_t)NB*4032);
    float* vi  = take((size_t)NB*4032);
    float* c1  = take((size_t)NB*32*25);
    float* c2  = take((size_t)NB*32*81);
    float* c3  = take((size_t)NB*32*289);
    float* c4  = take((size_t)NB*32*1089);
    float* wT1 = take(288);
    float* wT2 = take(9216);
    float* wT3 = take(9216);
    float* wT4 = take(9216);
    float* wT5 = take(576);
    (void)ws_size; (void)in_sizes; (void)n_in; (void)out_size;

    k_tables<<<16, 256, 0, stream>>>(Fr, Fi, acc);
    k_wprep<<<36, 256, 0, stream>>>(ct1_w, ct2_w, ct3_w, ct4_w, ct5_w,
                                    wT1, wT2, wT3, wT4, wT5);
    k_hyper<<<NB, 192, 0, stream>>>(kA, fc1_w1, fc1_b1, fc1_w2, fc1_b2,
                                    fc2_w1, fc2_b1, fc2_w2, fc2_b2, w1b, w2b);
    k_ct1c<<<(NB*25 + 255)/256, 256, 0, stream>>>(kA, wT1, ct1_b, c1);
    k_ct32c<5> <<<NB, 256, 0, stream>>>(c1, wT2, ct2_b, c2);
    k_ct32c<9> <<<NB, 256, 0, stream>>>(c2, wT3, ct3_b, c3);
    k_ct32c<17><<<NB, 256, 0, stream>>>(c3, wT4, ct4_b, c4);
    k_ct5v<<<NB, 256, 0, stream>>>(c4, wT5, ct5_b, vr, vi);
    k_solve<<<NB, 256, 0, stream>>>(x0, f, kA, w1b, w2b, Fr, Fi, vr, vi, acc);
    k_final<<<1, 64, 0, stream>>>(acc, out);
}

// Round 5
// 566.683 us; speedup vs baseline: 1.2363x; 1.2363x over previous
//
#include <hip/hip_runtime.h>
#include <math.h>

#define NB   256
#define ND   63
#define NN   3969        // 63*63
#define MIDc 32

__device__ __forceinline__ float gelu_f(float v){
    return 0.5f * v * (1.0f + erff(v * 0.70710678118654752440f));
}

#define FMA4(A, W, S) { (A).x=fmaf((W).x,(S),(A).x); (A).y=fmaf((W).y,(S),(A).y); \
                        (A).z=fmaf((W).z,(S),(A).z); (A).w=fmaf((W).w,(S),(A).w); }

union F4 { float4 v; float a[4]; };
union F2u { float2 v; float a[2]; };
union W16 { float4 v[4]; float a[16]; };

// ---------------- DFT tables (64x64 padded, row/col 63 zeroed) + acc reset ----
__global__ void k_tables(float* __restrict__ Fr, float* __restrict__ Fi, float* __restrict__ acc){
    int idx = blockIdx.x * blockDim.x + threadIdx.x;
    if (idx < 4096){
        int r = idx >> 6, c = idx & 63;
        float vr = 0.f, vi = 0.f;
        if (r < 63 && c < 63){
            int m = (r * c) % 63;
            float ang = 6.283185307179586f * (float)m / 63.0f;
            vr = cosf(ang); vi = -sinf(ang);
        }
        Fr[idx] = vr; Fi[idx] = vi;
    }
    if (idx == 0) acc[0] = 0.f;
}

// -------- weight prep: ct1 [1,32,3,3]->[tap][32]; ct2-4 ->[tap][ci][co32]; ct5 ->[tap][ci][2]
__global__ void k_wprep(const float* __restrict__ w1, const float* __restrict__ w2,
                        const float* __restrict__ w3, const float* __restrict__ w4,
                        const float* __restrict__ w5,
                        float* __restrict__ o1, float* __restrict__ o2,
                        float* __restrict__ o3, float* __restrict__ o4,
                        float* __restrict__ o5){
    int idx = blockIdx.x * blockDim.x + threadIdx.x;
    if (idx < 9216){
        int co = idx & 31, t = idx >> 5;
        int ci = t & 31, tap = t >> 5;
        int ky = tap / 3, kx = tap % 3;
        int src = ((ci*32 + co)*3 + ky)*3 + kx;
        o2[idx] = w2[src]; o3[idx] = w3[src]; o4[idx] = w4[src];
    }
    if (idx < 576){
        int co = idx & 1, t = idx >> 1;
        int ci = t & 31, tap = t >> 5;
        int ky = tap / 3, kx = tap % 3;
        o5[idx] = w5[((ci*2 + co)*3 + ky)*3 + kx];
    }
    if (idx < 288){
        int co = idx & 31, tap = idx >> 5;
        int ky = tap / 3, kx = tap % 3;
        o1[idx] = w1[(co*3 + ky)*3 + kx];
    }
}

// ---------------- hypernet: per-sample 9->100(gelu)->147, twice --------------
__global__ void k_hyper(const float* __restrict__ kA,
                        const float* __restrict__ w1a, const float* __restrict__ b1a,
                        const float* __restrict__ w2a, const float* __restrict__ b2a,
                        const float* __restrict__ w1b, const float* __restrict__ b1b,
                        const float* __restrict__ w2b, const float* __restrict__ b2b,
                        float* __restrict__ out1, float* __restrict__ out2){
    __shared__ float a[9];
    __shared__ float hid[100];
    int b = blockIdx.x, tid = threadIdx.x;
    if (tid < 9) a[tid] = kA[b*9 + tid];
    __syncthreads();
    if (tid < 100){
        float s = b1a[tid];
        #pragma unroll
        for (int i = 0; i < 9; i++) s = fmaf(a[i], w1a[i*100 + tid], s);
        hid[tid] = gelu_f(s);
    }
    __syncthreads();
    if (tid < 147){
        float s = b2a[tid];
        for (int k = 0; k < 100; k++) s = fmaf(hid[k], w2a[k*147 + tid], s);
        out1[b*147 + tid] = s;
    }
    __syncthreads();
    if (tid < 100){
        float s = b1b[tid];
        #pragma unroll
        for (int i = 0; i < 9; i++) s = fmaf(a[i], w1b[i*100 + tid], s);
        hid[tid] = gelu_f(s);
    }
    __syncthreads();
    if (tid < 147){
        float s = b2b[tid];
        for (int k = 0; k < 100; k++) s = fmaf(hid[k], w2b[k*147 + tid], s);
        out2[b*147 + tid] = s;
    }
}

// ---------------- ct1: 1->32, 3x3 in -> 5x5 out, stride2 pad1, gelu, channel-last
__global__ void k_ct1c(const float* __restrict__ kA, const float* __restrict__ wT1,
                       const float* __restrict__ bias, float* __restrict__ out){
    int idx = blockIdx.x * blockDim.x + threadIdx.x;
    if (idx >= NB*25) return;
    int p = idx % 25, b = idx / 25;
    int oy = p / 5, ox = p % 5;
    F4 acc[8];
    #pragma unroll
    for (int q = 0; q < 8; q++) acc[q].v = ((const float4*)bias)[q];
    int nky, kyA[2], iyA[2];
    if (oy & 1){ nky=2; kyA[0]=0; iyA[0]=(oy+1)/2; kyA[1]=2; iyA[1]=(oy-1)/2; }
    else       { nky=1; kyA[0]=1; iyA[0]=oy/2; kyA[1]=1; iyA[1]=0; }
    int nkx, kxA[2], ixA[2];
    if (ox & 1){ nkx=2; kxA[0]=0; ixA[0]=(ox+1)/2; kxA[1]=2; ixA[1]=(ox-1)/2; }
    else       { nkx=1; kxA[0]=1; ixA[0]=ox/2; kxA[1]=1; ixA[1]=0; }
    const float* ab = kA + b*9;
    for (int yi = 0; yi < nky; yi++)
    for (int xi = 0; xi < nkx; xi++){
        float v = ab[iyA[yi]*3 + ixA[xi]];
        const float4* wq = (const float4*)(wT1 + (kyA[yi]*3 + kxA[xi])*32);
        #pragma unroll
        for (int q = 0; q < 8; q++){ float4 w = wq[q]; FMA4(acc[q].v, w, v); }
    }
    float* ob = out + (size_t)idx*32;
    #pragma unroll
    for (int q = 0; q < 8; q++){
        float4 g; g.x=gelu_f(acc[q].a[0]); g.y=gelu_f(acc[q].a[1]);
        g.z=gelu_f(acc[q].a[2]); g.w=gelu_f(acc[q].a[3]);
        ((float4*)ob)[q] = g;
    }
}

// ------------- ct 32->32, stride2 pad1 k3, gelu. channel-last in/out. -------
template<int HIN>
__global__ __launch_bounds__(512) void k_ct32c(const float* __restrict__ in,
                                               const float* __restrict__ wT,
                                               const float* __restrict__ bias,
                                               float* __restrict__ out){
    constexpr int HOUT = 2*HIN - 1;
    constexpr int HINP = (HIN + 3) & ~3;
    constexpr int OCT  = (HOUT + 7) / 8;
    constexpr int UPR  = OCT * 4;              // 4 co-groups of 8
    constexpr int NODD = (HOUT/2) * UPR;
    constexpr int TOT  = HOUT * UPR;
    __shared__ __align__(16) float in_s[32*HIN*HINP + 16];
    __shared__ __align__(16) float w_s[9216];          // [tap][ci][co32]
    __shared__ __align__(16) float bias_s[32];
    const int b = blockIdx.x;
    const int tid = threadIdx.x;
    { const float4* src = (const float4*)wT; float4* dst = (float4*)w_s;
      for (int i = tid; i < 2304; i += 512) dst[i] = src[i]; }
    if (tid < 32) bias_s[tid] = bias[tid];
    { const float* gi = in + (size_t)b * (32*HIN*HIN);
      for (int i = tid; i < 32*HIN*HIN; i += 512){
        int ci = i & 31, px = i >> 5;
        int y = px / HIN, x = px % HIN;
        in_s[ci*(HIN*HINP) + y*HINP + x] = gi[i];
      } }
    __syncthreads();
    float* ob0 = out + (size_t)b*(HOUT*HOUT*32);
    for (int u = tid; u < TOT; u += 512){
        int r, s;
        if (u < NODD){ r = 2*(u/UPR) + 1; s = u % UPR; }
        else { int v = u - NODD; r = 2*(v/UPR); s = v % UPR; }
        const int m = s >> 2, cog = s & 3;
        const int x4 = 4*m;
        F4 acc[8][2];
        { float4 b0 = ((const float4*)bias_s)[cog*2];
          float4 b1 = ((const float4*)bias_s)[cog*2+1];
          #pragma unroll
          for (int p = 0; p < 8; p++){ acc[p][0].v = b0; acc[p][1].v = b1; } }
        int nky, kyA[2], iyA[2];
        if (r & 1){ int rI = r >> 1; nky = 2; kyA[0]=0; iyA[0]=rI+1; kyA[1]=2; iyA[1]=rI; }
        else      { nky = 1; kyA[0]=1; iyA[0]= r >> 1; kyA[1]=1; iyA[1]=0; }
        for (int yi = 0; yi < nky; yi++){
            const float* ip = in_s + iyA[yi]*HINP + x4;
            const float* wp = w_s + kyA[yi]*3*1024 + cog*8;
            #pragma unroll 2
            for (int ci = 0; ci < 32; ci++){
                F4 iv0, iv1;
                iv0.v = *(const float4*)(ip);
                iv1.v = *(const float4*)(ip + 4);
                float4 w0a = *(const float4*)(wp);
                float4 w0b = *(const float4*)(wp + 4);
                float4 w1a = *(const float4*)(wp + 1024);
                float4 w1b = *(const float4*)(wp + 1028);
                float4 w2a = *(const float4*)(wp + 2048);
                float4 w2b = *(const float4*)(wp + 2052);
                #pragma unroll
                for (int p = 0; p < 4; p++){
                    float ev = iv0.a[p];
                    FMA4(acc[2*p][0].v, w1a, ev);
                    FMA4(acc[2*p][1].v, w1b, ev);
                    float o0 = (p < 3) ? iv0.a[p+1] : iv1.a[0];
                    FMA4(acc[2*p+1][0].v, w0a, o0);
                    FMA4(acc[2*p+1][1].v, w0b, o0);
                    FMA4(acc[2*p+1][0].v, w2a, ev);
                    FMA4(acc[2*p+1][1].v, w2b, ev);
                }
                ip += HIN*HINP;
                wp += 32;
            }
        }
        int lim = HOUT - 8*m; if (lim > 8) lim = 8;
        float* ob = ob0 + ((size_t)r*HOUT + 8*m)*32 + cog*8;
        for (int e = 0; e < lim; e++){
            float4 g0, g1;
            g0.x=gelu_f(acc[e][0].a[0]); g0.y=gelu_f(acc[e][0].a[1]);
            g0.z=gelu_f(acc[e][0].a[2]); g0.w=gelu_f(acc[e][0].a[3]);
            g1.x=gelu_f(acc[e][1].a[0]); g1.y=gelu_f(acc[e][1].a[1]);
            g1.z=gelu_f(acc[e][1].a[2]); g1.w=gelu_f(acc[e][1].a[3]);
            *(float4*)(ob + (size_t)e*32)     = g0;
            *(float4*)(ob + (size_t)e*32 + 4) = g1;
        }
    }
}

// ---- ct5 (32->2, stride2 pad2 k3) + buildv fused, block = sample -----------
__global__ __launch_bounds__(256) void k_ct5v(const float* __restrict__ in,
                                              const float* __restrict__ wT5,
                                              const float* __restrict__ bias,
                                              float* __restrict__ vr,
                                              float* __restrict__ vi){
    __shared__ float ws5[576];
    __shared__ float c5s[2*NN];
    const int b = blockIdx.x, tid = threadIdx.x;
    for (int i = tid; i < 576; i += 256) ws5[i] = wT5[i];
    __syncthreads();
    const float* ib = in + (size_t)b * (32*33*33);
    float b0 = bias[0], b1 = bias[1];
    for (int p = tid; p < NN; p += 256){
        int oy = p / ND, ox = p % ND;
        float a0 = b0, a1 = b1;
        int nky, kyA[2], iyA[2];
        if ((oy & 1) == 0){ nky=2; kyA[0]=0; iyA[0]=oy/2+1; kyA[1]=2; iyA[1]=oy/2; }
        else              { nky=1; kyA[0]=1; iyA[0]=(oy+1)/2; kyA[1]=1; iyA[1]=0; }
        int nkx, kxA[2], ixA[2];
        if ((ox & 1) == 0){ nkx=2; kxA[0]=0; ixA[0]=ox/2+1; kxA[1]=2; ixA[1]=ox/2; }
        else              { nkx=1; kxA[0]=1; ixA[0]=(ox+1)/2; kxA[1]=1; ixA[1]=0; }
        for (int yi = 0; yi < nky; yi++)
        for (int xi = 0; xi < nkx; xi++){
            const float* ip = ib + ((size_t)iyA[yi]*33 + ixA[xi])*32;
            const float* wp = ws5 + (kyA[yi]*3 + kxA[xi])*64;
            #pragma unroll 8
            for (int ci = 0; ci < 32; ci++){
                float v = ip[ci];
                a0 = fmaf(v, wp[ci*2],   a0);
                a1 = fmaf(v, wp[ci*2+1], a1);
            }
        }
        c5s[p]      = a0;
        c5s[NN + p] = a1;
    }
    __syncthreads();
    const float sc = 1.0f / 3969.0f;
    for (int i = tid; i < NN; i += 256){
        int ky = i / ND, kx = i % ND;
        float re, im;
        if (kx <= 31){ re = c5s[2*i]; im = c5s[2*i+1]; }
        else {
            int sy = (ND - ky) % ND, sx = ND - kx;
            int o = 2*(sy*ND + sx); re = c5s[o]; im = -c5s[o+1];
        }
        vr[(size_t)b*4032 + ky*64 + kx] = re * sc;
        vi[(size_t)b*4032 + ky*64 + kx] = im * sc;
    }
}

// ---------------- mega solver: 5 x (smoother ; x += hcorrect(residual)) -----
// Block = sample, 512 threads (8 waves/CU). x in LDS. DFT tiles 2x4/lane.
// Transposed B-plane stores use rotation swizzle col' = (kt + row>>2) & 31
// (conflict-free); smoother scratch row stride 68 floats (odd f4-stride).
__global__ __launch_bounds__(512) void k_solve(const float* __restrict__ x0g,
                                               const float* __restrict__ f,
                                               const float* __restrict__ kAg,
                                               const float* __restrict__ w1g,
                                               const float* __restrict__ w2g,
                                               const float* __restrict__ Frg,
                                               const float* __restrict__ Fig,
                                               const float* __restrict__ vrg,
                                               const float* __restrict__ vig,
                                               float* __restrict__ accg){
    __shared__ __align__(16) float U[16384];     // 64 KB union
    __shared__ __align__(16) float xs[4032];     // 63 x 64
    __shared__ float w1s[147], w2s[147], red[8];
    const int b = blockIdx.x, tid = threadIdx.x;
    float* rs = U;                // 63 x 68 (+pad)
    float* tc = U + 4352;         // 63 x 68 (+pad)
    float* sA = U;                // 2 x 4096 (r/Mr, Mi)
    float* sB = U + 8192;         // 2 x 4096 (Ttr/Ptr, Tti/Pti)
    float4* A40 = (float4*)sA;  float4* A41 = (float4*)(sA + 4096);
    float2* B2r = (float2*)sB;  float2* B2i = (float2*)(sB + 4096);
    const float4* F4r = (const float4*)Frg;
    const float4* F4i = (const float4*)Fig;
    const float2* F2r = (const float2*)Frg;
    const float2* F2i = (const float2*)Fig;
    const float* fg = f + (size_t)b*NN;
    float ka[9];
    #pragma unroll
    for (int i = 0; i < 9; i++) ka[i] = kAg[b*9 + i];
    if (tid < 147){ w1s[tid] = w1g[b*147 + tid]; w2s[tid] = w2g[b*147 + tid]; }
    for (int i = tid; i < NN; i += 512) xs[(i/ND)*64 + (i%ND)] = x0g[(size_t)b*NN + i];
    __syncthreads();

    const int kt = tid >> 4, ct = tid & 15;   // kt 0..31, ct 0..15
    const int k0 = kt * 2, c0 = ct * 4;

    for (int it = 0; it < 5; it++){
        // ================= smoother =================
        { float4 z = {0.f,0.f,0.f,0.f};
          float4* U4 = (float4*)U;
          for (int i = tid; i < 2176; i += 512) U4[i] = z; }   // zero rs+tc
        __syncthreads();
        for (int i = tid; i < NN; i += 512){
            int y = i / ND, xx = i % ND;
            float s = 0.f;
            #pragma unroll
            for (int dy = 0; dy < 3; dy++){
                int u = y + dy;
                #pragma unroll
                for (int dx = 0; dx < 3; dx++){
                    int v = xx + dx;
                    float p;
                    if (u == 64 || v == 64)    p = 1.0f;
                    else if (u == 0 || v == 0) p = 0.0f;
                    else                       p = xs[(u-1)*64 + (v-1)];
                    s = fmaf(p, ka[dy*3 + dx], s);
                }
            }
            rs[y*68 + 3 + xx] = fg[i] - s;
        }
        __syncthreads();
        const bool act = tid < 504;
        const int y0 = tid >> 3, x0c = 8*(tid & 7);
        float acc2[8] = {};
        for (int c = 0; c < 3; c++){
            if (act){
                float a1[8] = {};
                for (int dy = 0; dy < 7; dy++){
                    int ry = y0 + dy - 3;
                    if (ry < 0 || ry >= 63) continue;
                    W16 w16;
                    const float4* rp = (const float4*)(rs + ry*68 + x0c);
                    w16.v[0]=rp[0]; w16.v[1]=rp[1]; w16.v[2]=rp[2]; w16.v[3]=rp[3];
                    #pragma unroll
                    for (int dx = 0; dx < 7; dx++){
                        float wv = w1s[c*49 + dy*7 + dx];
                        #pragma unroll
                        for (int t = 0; t < 8; t++) a1[t] = fmaf(wv, w16.a[t+dx], a1[t]);
                    }
                }
                int nw = 63 - x0c; if (nw > 8) nw = 8;
                for (int t = 0; t < nw; t++) tc[y0*68 + 3 + x0c + t] = a1[t];
            }
            __syncthreads();
            if (act){
                for (int dy = 0; dy < 7; dy++){
                    int ry = y0 + dy - 3;
                    if (ry < 0 || ry >= 63) continue;
                    W16 w16;
                    const float4* tp = (const float4*)(tc + ry*68 + x0c);
                    w16.v[0]=tp[0]; w16.v[1]=tp[1]; w16.v[2]=tp[2]; w16.v[3]=tp[3];
                    #pragma unroll
                    for (int dx = 0; dx < 7; dx++){
                        float wv = w2s[c*49 + dy*7 + dx];
                        #pragma unroll
                        for (int t = 0; t < 8; t++) acc2[t] = fmaf(wv, w16.a[t+dx], acc2[t]);
                    }
                }
            }
            __syncthreads();
        }
        if (act){
            int nw = 63 - x0c; if (nw > 8) nw = 8;
            for (int t = 0; t < nw; t++) xs[y0*64 + x0c + t] += acc2[t];
        }
        __syncthreads();
        // ============ residual of updated x -> sA plane0 ============
        for (int i = tid; i < 4096; i += 512){
            int y = i >> 6, xx = i & 63;
            float val = 0.f;
            if (y < 63 && xx < 63){
                float s = 0.f;
                #pragma unroll
                for (int dy = 0; dy < 3; dy++){
                    int u = y + dy;
                    #pragma unroll
                    for (int dx = 0; dx < 3; dx++){
                        int v = xx + dx;
                        float p;
                        if (u == 64 || v == 64)    p = 1.0f;
                        else if (u == 0 || v == 0) p = 0.0f;
                        else                       p = xs[(u-1)*64 + (v-1)];
                        s = fmaf(p, ka[dy*3 + dx], s);
                    }
                }
                val = fg[y*ND + xx] - s;
            }
            sA[i] = val;
        }
        __syncthreads();
        // ============ spectral correction ============
        {   // Phase A: T = F r -> Tt (swizzled) in sB
            float tr[2][4] = {}, ti[2][4] = {};
            for (int m = 0; m < 63; m++){
                F2u fr, fi; F4 rv;
                fr.v = F2r[m*32 + kt]; fi.v = F2i[m*32 + kt];
                rv.v = A40[m*16 + ct];
                #pragma unroll
                for (int i = 0; i < 2; i++)
                    #pragma unroll
                    for (int j = 0; j < 4; j++){
                        tr[i][j] = fmaf(fr.a[i], rv.a[j], tr[i][j]);
                        ti[i][j] = fmaf(fi.a[i], rv.a[j], ti[i][j]);
                    }
            }
            #pragma unroll
            for (int j = 0; j < 4; j++){
                int n = c0 + j;
                int cw = (kt + ct) & 31;
                B2r[n*32 + cw] = make_float2(tr[0][j], tr[1][j]);
                B2i[n*32 + cw] = make_float2(ti[0][j], ti[1][j]);
            }
        }
        __syncthreads();
        {   // Phase B: R = T F ; M = R .* v -> sA
            float Rr[2][4] = {}, Ri[2][4] = {};
            for (int n = 0; n < 63; n++){
                int cw = (kt + (n >> 2)) & 31;
                F2u ar, ai; F4 fr, fi;
                ar.v = B2r[n*32 + cw]; ai.v = B2i[n*32 + cw];
                fr.v = F4r[n*16 + ct]; fi.v = F4i[n*16 + ct];
                #pragma unroll
                for (int i = 0; i < 2; i++)
                    #pragma unroll
                    for (int j = 0; j < 4; j++){
                        Rr[i][j] = fmaf(ar.a[i], fr.a[j], Rr[i][j]);
                        Rr[i][j] = fmaf(-ai.a[i], fi.a[j], Rr[i][j]);
                        Ri[i][j] = fmaf(ar.a[i], fi.a[j], Ri[i][j]);
                        Ri[i][j] = fmaf(ai.a[i], fr.a[j], Ri[i][j]);
                    }
            }
            const float4* v4r = (const float4*)(vrg + (size_t)b*4032);
            const float4* v4i = (const float4*)(vig + (size_t)b*4032);
            #pragma unroll
            for (int i = 0; i < 2; i++){
                int k = k0 + i;
                int kk = k < 63 ? k : 62;
                F4 wr, wi, mr, mi;
                wr.v = v4r[kk*16 + ct]; wi.v = v4i[kk*16 + ct];
                #pragma unroll
                for (int j = 0; j < 4; j++){
                    mr.a[j] = Rr[i][j]*wr.a[j] - Ri[i][j]*wi.a[j];
                    mi.a[j] = Rr[i][j]*wi.a[j] + Ri[i][j]*wr.a[j];
                }
                A40[k*16 + ct] = mr.v;
                A41[k*16 + ct] = mi.v;
            }
        }
        __syncthreads();
        {   // Phase D: P = conj(F) M -> Pt (swizzled) in sB
            float Pr[2][4] = {}, Pi[2][4] = {};
            for (int n = 0; n < 63; n++){
                F2u fr, fi; F4 mr, mi;
                fr.v = F2r[n*32 + kt]; fi.v = F2i[n*32 + kt];
                mr.v = A40[n*16 + ct]; mi.v = A41[n*16 + ct];
                #pragma unroll
                for (int i = 0; i < 2; i++)
                    #pragma unroll
                    for (int j = 0; j < 4; j++){
                        Pr[i][j] = fmaf(fr.a[i], mr.a[j], Pr[i][j]);
                        Pr[i][j] = fmaf(fi.a[i], mi.a[j], Pr[i][j]);
                        Pi[i][j] = fmaf(fr.a[i], mi.a[j], Pi[i][j]);
                        Pi[i][j] = fmaf(-fi.a[i], mr.a[j], Pi[i][j]);
                    }
            }
            #pragma unroll
            for (int j = 0; j < 4; j++){
                int l = c0 + j;
                int cw = (kt + ct) & 31;
                B2r[l*32 + cw] = make_float2(Pr[0][j], Pr[1][j]);
                B2i[l*32 + cw] = make_float2(Pi[0][j], Pi[1][j]);
            }
        }
        __syncthreads();
        {   // Phase E: y = Re(P conj(F)) ; x += y
            float yv[2][4] = {};
            for (int l = 0; l < 63; l++){
                int cw = (kt + (l >> 2)) & 31;
                F2u pr, pi; F4 fr, fi;
                pr.v = B2r[l*32 + cw]; pi.v = B2i[l*32 + cw];
                fr.v = F4r[l*16 + ct]; fi.v = F4i[l*16 + ct];
                #pragma unroll
                for (int i = 0; i < 2; i++)
                    #pragma unroll
                    for (int j = 0; j < 4; j++){
                        yv[i][j] = fmaf(pr.a[i], fr.a[j], yv[i][j]);
                        yv[i][j] = fmaf(pi.a[i], fi.a[j], yv[i][j]);
                    }
            }
            #pragma unroll
            for (int i = 0; i < 2; i++){
                int p = k0 + i;
                if (p < 63){
                    #pragma unroll
                    for (int j = 0; j < 4; j++){
                        int q = c0 + j;
                        if (q < 63) xs[p*64 + q] += yv[i][j];
                    }
                }
            }
        }
        __syncthreads();
    }
    // ================= final residual + norm partial =================
    float s = 0.f;
    for (int i = tid; i < NN; i += 512){
        int y = i / ND, xx = i % ND;
        float cv = 0.f;
        #pragma unroll
        for (int dy = 0; dy < 3; dy++){
            int u = y + dy;
            #pragma unroll
            for (int dx = 0; dx < 3; dx++){
                int v = xx + dx;
                float p;
                if (u == 64 || v == 64)    p = 1.0f;
                else if (u == 0 || v == 0) p = 0.0f;
                else                       p = xs[(u-1)*64 + (v-1)];
                cv = fmaf(p, ka[dy*3 + dx], cv);
            }
        }
        float r = fg[i] - cv;
        s = fmaf(r, r, s);
    }
    #pragma unroll
    for (int off = 32; off > 0; off >>= 1) s += __shfl_down(s, off, 64);
    int lane = tid & 63, w = tid >> 6;
    if (lane == 0) red[w] = s;
    __syncthreads();
    if (tid == 0){
        float t = 0.f;
        #pragma unroll
        for (int i = 0; i < 8; i++) t += red[i];
        atomicAdd(accg, t);
    }
}

__global__ void k_final(const float* __restrict__ acc, float* __restrict__ out){
    if (threadIdx.x == 0 && blockIdx.x == 0) out[0] = sqrtf(acc[0]) * (1.0f/256.0f);
}

// ---------------- host ------------------------------------------------------
extern "C" void kernel_launch(void* const* d_in, const int* in_sizes, int n_in,
                              void* d_out, int out_size, void* d_ws, size_t ws_size,
                              hipStream_t stream){
    const float* x0     = (const float*)d_in[0];
    const float* f      = (const float*)d_in[1];
    const float* kA     = (const float*)d_in[2];
    const float* fc1_w1 = (const float*)d_in[3];
    const float* fc1_b1 = (const float*)d_in[4];
    const float* fc1_w2 = (const float*)d_in[5];
    const float* fc1_b2 = (const float*)d_in[6];
    const float* fc2_w1 = (const float*)d_in[7];
    const float* fc2_b1 = (const float*)d_in[8];
    const float* fc2_w2 = (const float*)d_in[9];
    const float* fc2_b2 = (const float*)d_in[10];
    const float* ct1_w  = (const float*)d_in[11];
    const float* ct1_b  = (const float*)d_in[12];
    const float* ct2_w  = (const float*)d_in[13];
    const float* ct2_b  = (const float*)d_in[14];
    const float* ct3_w  = (const float*)d_in[15];
    const float* ct3_b  = (const float*)d_in[16];
    const float* ct4_w  = (const float*)d_in[17];
    const float* ct4_b  = (const float*)d_in[18];
    const float* ct5_w  = (const float*)d_in[19];
    const float* ct5_b  = (const float*)d_in[20];
    float* out = (float*)d_out;

    float* ws = (float*)d_ws;
    size_t off = 0;
    auto take = [&](size_t n){ float* p = ws + off; off += (n + 63) & ~(size_t)63; return p; };
    float* Fr  = take(4096);
    float* Fi  = take(4096);
    float* acc = take(64);
    float* w1b = take((size_t)NB*147);
    float* w2b = take((size_t)NB*147);
    float* vr  = take((size_t)NB*4032);
    float* vi  = take((size_t)NB*4032);
    float* c1  = take((size_t)NB*32*25);
    float* c2  = take((size_t)NB*32*81);
    float* c3  = take((size_t)NB*32*289);
    float* c4  = take((size_t)NB*32*1089);
    float* wT1 = take(288);
    float* wT2 = take(9216);
    float* wT3 = take(9216);
    float* wT4 = take(9216);
    float* wT5 = take(576);
    (void)ws_size; (void)in_sizes; (void)n_in; (void)out_size;

    k_tables<<<16, 256, 0, stream>>>(Fr, Fi, acc);
    k_wprep<<<36, 256, 0, stream>>>(ct1_w, ct2_w, ct3_w, ct4_w, ct5_w,
                                    wT1, wT2, wT3, wT4, wT5);
    k_hyper<<<NB, 192, 0, stream>>>(kA, fc1_w1, fc1_b1, fc1_w2, fc1_b2,
                                    fc2_w1, fc2_b1, fc2_w2, fc2_b2, w1b, w2b);
    k_ct1c<<<(NB*25 + 255)/256, 256, 0, stream>>>(kA, wT1, ct1_b, c1);
    k_ct32c<5> <<<NB, 512, 0, stream>>>(c1, wT2, ct2_b, c2);
    k_ct32c<9> <<<NB, 512, 0, stream>>>(c2, wT3, ct3_b, c3);
    k_ct32c<17><<<NB, 512, 0, stream>>>(c3, wT4, ct4_b, c4);
    k_ct5v<<<NB, 256, 0, stream>>>(c4, wT5, ct5_b, vr, vi);
    k_solve<<<NB, 512, 0, stream>>>(x0, f, kA, w1b, w2b, Fr, Fi, vr, vi, acc);
    k_final<<<1, 64, 0, stream>>>(acc, out);
}